// Round 8
// baseline (415.870 us; speedup 1.0000x reference)
//
#include <hip/hip_runtime.h>
#include <hip/hip_bf16.h>

// Graph attention: B=8,H=8,N=1024,d=128. fp32 in/out, bf16 MFMA compute.
// R17: BN=128 single-block-per-tile rework combining every proven mechanism:
//  - 1024-thread block (16 waves = 4 rowg x 4 colg) computes one 128-q tile.
//    Per-wave acc = s(16)+o(16) = 32 regs (was 64) -> real register margin at
//    the 128-reg/wave cap (16 waves/CU). No persistent qf.
//  - ALL operands in odd-stride padded LDS [128][130] (R16-proven ZERO bank
//    conflicts): Qs + Kt + Vt + Ps = 130 KB, 1 block/CU = 16 waves/CU.
//    Q staged ONCE coalesced (fp32->bf16); K/V reg-staged per iter (T14):
//    loads issued at iter top, K' ds_write after bar2 (Kt dead), V' after
//    bar3 (Vt dead). 3 raw barriers + lgkmcnt waits; no vmcnt gymnastics.
//  - BN=128: 8 iterations; per-lane softmax work halves (16 waves share it);
//    32x32x16 MFMA layouts identical to R12-proven mapping.
//  - adj bitmask u32 column-major (1 dword/lane/iter), R11-proven.
//  - rs row-sums recovered from PV A-fragments + shfl_xor(32), R14-proven.
// ws: K 16.78 + V 16.78 + adj 0.125 = 33.7 MB. Fallback (R8) if ws smaller.

typedef __bf16 bf16x8 __attribute__((ext_vector_type(8)));
typedef float  f32x4  __attribute__((ext_vector_type(4)));
typedef float  f32x16 __attribute__((ext_vector_type(16)));
typedef unsigned int u32;
typedef u32 u32x4 __attribute__((ext_vector_type(4)));

#define NSEQ 1024
#define DH   128
#define C1 0.1803368801111244f         // 0.125 * log2(e)
#define C2 11.5415603271110070f        // 8 * log2(e)
#define LD2 130                        // padded stride (65 dw, odd) -> no conflicts
#define NT2 8                          // 8 kv-tiles of 128
#define TILE2 (128 * 128)              // 16384 bf16 = 32 KB

__device__ __forceinline__ float f4get(const float4& v, int c) {
    return (c == 0) ? v.x : (c == 1) ? v.y : (c == 2) ? v.z : v.w;
}

__device__ __forceinline__ bf16x8 cvt8(const float* src) {
    float4 a = *(const float4*)src;
    float4 b = *(const float4*)(src + 4);
    bf16x8 w;
    w[0]=(__bf16)a.x; w[1]=(__bf16)a.y; w[2]=(__bf16)a.z; w[3]=(__bf16)a.w;
    w[4]=(__bf16)b.x; w[5]=(__bf16)b.y; w[6]=(__bf16)b.z; w[7]=(__bf16)b.w;
    return w;
}

// ---------------- pre-pass: K tiles [kv][k], V tiles [d][kv], adj bits ------
__global__ __launch_bounds__(256)
void prepack2(const float* __restrict__ K, const float* __restrict__ V,
              __bf16* __restrict__ Kws, __bf16* __restrict__ Vws,
              u32* __restrict__ adjc, const int* __restrict__ adj)
{
    const int tid = threadIdx.x;
    const int id  = blockIdx.x;

    if (id >= 512) {
        // adjc[kv][rg32] u32: bit j = adj[rg32*32 + j][kv] > 0
        const int idx  = id - 512;           // 0..127
        const int rg32 = idx & 31;
        const int kv   = (idx >> 5) * 256 + tid;
        u32 w = 0;
        #pragma unroll
        for (int j = 0; j < 32; ++j)
            w |= (u32)(adj[(size_t)(rg32 * 32 + j) * NSEQ + kv] > 0) << j;
        adjc[(size_t)kv * 32 + rg32] = w;
        return;
    }

    // K/V tile: bh = id>>3, t = id&7
    const size_t gbase = (size_t)(id >> 3) * NSEQ * DH + (size_t)(id & 7) * 128 * DH;
    __bf16* ko = Kws + (size_t)id * TILE2;
    __bf16* vo = Vws + (size_t)id * TILE2;

    // K tile 128x128 plain row-major [kv][k], coalesced
    #pragma unroll
    for (int p = 0; p < 8; ++p) {
        const int r = p * 16 + (tid >> 4);
        const int c = tid & 15;
        *(bf16x8*)(ko + r * 128 + c * 8) = cvt8(K + gbase + (size_t)r * DH + c * 8);
    }
    // V tile transposed [d][kv] 128x128
    {
        const int vdb = tid & 31;          // d block (4 d each)
        const int vkb = tid >> 5;          // kv block of 16
        #pragma unroll
        for (int pass = 0; pass < 2; ++pass) {
            float4 vr[8];
            #pragma unroll
            for (int j = 0; j < 8; ++j)
                vr[j] = *(const float4*)(V + gbase
                         + (size_t)(vkb * 16 + pass * 8 + j) * DH + vdb * 4);
            #pragma unroll
            for (int c = 0; c < 4; ++c) {
                const int d = vdb * 4 + c;
                bf16x8 w;
                #pragma unroll
                for (int j = 0; j < 8; ++j) w[j] = (__bf16)f4get(vr[j], c);
                *(bf16x8*)(vo + d * 128 + vkb * 16 + pass * 8) = w;
            }
        }
    }
}

// ---------------- hot kernel: 16-wave BN=128 padded-LDS flash attention -----
__global__ __launch_bounds__(1024, 4)
void attn_big(const float* __restrict__ Q, const __bf16* __restrict__ Kws,
              const __bf16* __restrict__ Vws, const u32* __restrict__ adjc,
              float* __restrict__ out)
{
    __shared__ __attribute__((aligned(16))) __bf16 Qs[128 * LD2];  // 33.3 KB
    __shared__ __attribute__((aligned(16))) __bf16 Kt[128 * LD2];  // 33.3 KB
    __shared__ __attribute__((aligned(16))) __bf16 Vt[128 * LD2];  // 33.3 KB
    __shared__ __attribute__((aligned(16))) __bf16 Ps[128 * LD2];  // 33.3 KB

    const int tid  = threadIdx.x;
    const int wave = tid >> 6;            // 0..15
    const int lane = tid & 63;
    const int l31  = lane & 31;
    const int hi   = lane >> 5;           // 0/1
    const int rowg = wave >> 2;           // 0..3: q-rows rowg*32..+31
    const int cg   = wave & 3;            // 0..3: kv cols (S) / d cols (PV)

    const int id = blockIdx.x;            // XCD swizzle (R6-proven)
    const int bh = (id & 7) * 8 + ((id >> 3) & 7);
    const int q0 = (id >> 6) * 128;
    const size_t base = (size_t)bh * NSEQ * DH;

    // ---- staging coords (linear halves; padded ds_write) ----
    const int sr = tid >> 4;              // 0..63
    const int sc = (tid & 15) * 8;        // 0..120
    const __bf16* kg = Kws + (size_t)(bh * NT2) * TILE2 + sr * 128 + sc;
    const __bf16* vg = Vws + (size_t)(bh * NT2) * TILE2 + sr * 128 + sc;
    __bf16* kd0 = &Kt[sr * LD2 + sc];
    __bf16* kd1 = &Kt[(64 + sr) * LD2 + sc];
    __bf16* vd0 = &Vt[sr * LD2 + sc];
    __bf16* vd1 = &Vt[(64 + sr) * LD2 + sc];

    // ---- compute-phase LDS pointers (all odd-stride -> conflict-free) ----
    const __bf16* qr = &Qs[(rowg * 32 + l31) * LD2 + hi * 8];  // S A-frag
    const __bf16* kr = &Kt[(cg * 32 + l31) * LD2 + hi * 8];    // S B-frag
    const __bf16* pr = &Ps[(rowg * 32 + l31) * LD2 + hi * 8];  // PV A-frag
    const __bf16* vp = &Vt[(cg * 32 + l31) * LD2 + hi * 8];    // PV B-frag
    __bf16* pw = &Ps[(rowg * 32 + 4 * hi) * LD2 + cg * 32 + l31];
    const u32* ap = adjc + (size_t)(cg * 32 + l31) * 32 + (q0 >> 5) + rowg;

    f32x16 o;
    #pragma unroll
    for (int i = 0; i < 16; ++i) o[i] = 0.f;
    float rs = 0.f;

    // ---- prologue: stage Q (fp32->bf16, coalesced) + K0/V0 ----
    {
        const float* qsrc = Q + base + (size_t)(q0 + (tid >> 3)) * DH + (tid & 7) * 16;
        __bf16* qdst = &Qs[(tid >> 3) * LD2 + (tid & 7) * 16];
        *(bf16x8*)qdst       = cvt8(qsrc);
        *(bf16x8*)(qdst + 8) = cvt8(qsrc + 8);
        bf16x8 ka = *(const bf16x8*)(kg);
        bf16x8 kb = *(const bf16x8*)(kg + 8192);
        bf16x8 va = *(const bf16x8*)(vg);
        bf16x8 vb = *(const bf16x8*)(vg + 8192);
        *(bf16x8*)kd0 = ka;  *(bf16x8*)kd1 = kb;
        *(bf16x8*)vd0 = va;  *(bf16x8*)vd1 = vb;
    }

    for (int kt = 0; kt < NT2; ++kt) {
        // ---- bar1: staged ds_writes drained + visible ----
        __builtin_amdgcn_sched_barrier(0);
        asm volatile("s_waitcnt lgkmcnt(0)" ::: "memory");
        __builtin_amdgcn_s_barrier();
        __builtin_amdgcn_sched_barrier(0);

        const u32 am = ap[kt * 4096];

        // ---- issue next-tile loads to regs (latency spans the iteration) ----
        const int st = (kt < NT2 - 1) ? (kt + 1) : (NT2 - 1);  // last: dead reload
        const __bf16* kgs = kg + (size_t)st * TILE2;
        const __bf16* vgs = vg + (size_t)st * TILE2;
        bf16x8 ka = *(const bf16x8*)(kgs);
        bf16x8 kb = *(const bf16x8*)(kgs + 8192);
        bf16x8 va = *(const bf16x8*)(vgs);
        bf16x8 vb = *(const bf16x8*)(vgs + 8192);
        __builtin_amdgcn_sched_barrier(0);

        // ---- S = Q K^T : 32x32 tile per wave, 8 chained MFMA over k=128 ----
        f32x16 s;
        #pragma unroll
        for (int i = 0; i < 16; ++i) s[i] = 0.f;
        __builtin_amdgcn_s_setprio(1);
        #pragma unroll
        for (int ks = 0; ks < 8; ++ks) {
            bf16x8 qa = *(const bf16x8*)(qr + ks * 16);
            bf16x8 kf = *(const bf16x8*)(kr + ks * 16);
            s = __builtin_amdgcn_mfma_f32_32x32x16_bf16(qa, kf, s, 0, 0, 0);
        }
        __builtin_amdgcn_s_setprio(0);

        // ---- masked softmax; P into padded Ps (plain writes) ----
        // C/D: col kv = cg*32+l31, row = rowg*32 + rlo + 4*hi
        {
            const u32 m2 = am >> (hi * 4);
            #pragma unroll
            for (int reg = 0; reg < 16; ++reg) {
                const int rlo = (reg & 3) + 8 * (reg >> 2);    // compile-time
                float p = exp2f(__builtin_fmaf(s[reg], C1, -C2));
                p = ((m2 >> rlo) & 1u) ? p : 0.f;
                pw[rlo * LD2] = (__bf16)p;
            }
        }

        // ---- bar2: Ps visible; all waves past S -> Kt dead ----
        __builtin_amdgcn_sched_barrier(0);
        asm volatile("s_waitcnt lgkmcnt(0)" ::: "memory");
        __builtin_amdgcn_s_barrier();
        __builtin_amdgcn_sched_barrier(0);

        // ---- write K' (overlaps PV; Kt not read until next S) ----
        *(bf16x8*)kd0 = ka;
        *(bf16x8*)kd1 = kb;
        __builtin_amdgcn_sched_barrier(0);

        // ---- O += P V : 32x32 tile per wave, 8 chained MFMA over kv=128 ----
        // rs: lane covers kv {16k + hi*8 + j}; lane^32 the complement.
        __builtin_amdgcn_s_setprio(1);
        #pragma unroll
        for (int kstep = 0; kstep < 8; ++kstep) {
            bf16x8 pa = *(const bf16x8*)(pr + kstep * 16);
            bf16x8 vf = *(const bf16x8*)(vp + kstep * 16);
            o = __builtin_amdgcn_mfma_f32_32x32x16_bf16(pa, vf, o, 0, 0, 0);
            u32x4 pu = __builtin_bit_cast(u32x4, pa);
            #pragma unroll
            for (int w = 0; w < 4; ++w) {
                const u32 d = pu[w];
                rs += __uint_as_float(d << 16);
                rs += __uint_as_float(d & 0xffff0000u);
            }
        }
        __builtin_amdgcn_s_setprio(0);

        // ---- bar3: all PV reads done -> Vt dead; then write V' ----
        __builtin_amdgcn_sched_barrier(0);
        __builtin_amdgcn_s_barrier();
        __builtin_amdgcn_sched_barrier(0);
        *(bf16x8*)vd0 = va;
        *(bf16x8*)vd1 = vb;
        // next iter's bar1 lgkmcnt(0) covers these writes
    }

    // ---- epilogue: complete row sums, broadcast via LDS, scale + store ----
    rs += __shfl_xor(rs, 32);             // full sum of row rowg*32 + l31
    __syncthreads();                      // drain last staged writes; Ps dead
    float* Ls = (float*)&Ps[0];
    if (cg == 0 && lane < 32)
        Ls[rowg * 32 + l31] = rs;
    __syncthreads();
    #pragma unroll
    for (int reg = 0; reg < 16; ++reg) {
        const int row = rowg * 32 + (reg & 3) + 8 * (reg >> 2) + 4 * hi;
        const float linv = 1.0f / fmaxf(Ls[row], 1e-30f);
        out[base + (size_t)(q0 + row) * DH + cg * 32 + l31] = o[reg] * linv;
    }
}

// ---------------- fallback (R8-proven) if ws too small ----------------------
#define BN 64
#define NKT 16
#define KS_STRIDE 136
#define VT_STRIDE 64
#define PS_STRIDE 72

__global__ __launch_bounds__(256, 4)
void attn_fallback(const float* __restrict__ Q, const float* __restrict__ K,
                   const float* __restrict__ V, const int* __restrict__ adj,
                   float* __restrict__ out)
{
    __shared__ __attribute__((aligned(16))) __bf16 KsP[BN * KS_STRIDE];
    __shared__ __attribute__((aligned(16))) __bf16 Vts[DH * VT_STRIDE];
    const int tid = threadIdx.x;
    const int wave = tid >> 6, lane = tid & 63, n16 = lane & 15, quad = lane >> 4;
    const int id = blockIdx.x;
    const int bh = (id & 7) * 8 + ((id >> 3) & 7);
    const int q0 = (id >> 6) * 64;
    const size_t base = (size_t)bh * NSEQ * DH;
    const int rp = tid >> 4, kcol = (tid & 15) * 8, db = tid & 31, kvb = tid >> 5;
    bf16x8 qf[4];
    #pragma unroll
    for (int ks = 0; ks < 4; ++ks)
        qf[ks] = cvt8(Q + base + (size_t)(q0 + wave * 16 + n16) * DH + ks * 32 + quad * 8);
    f32x4 o[8];
    #pragma unroll
    for (int i = 0; i < 8; ++i) o[i] = (f32x4){0.f, 0.f, 0.f, 0.f};
    float lp[4] = {0.f, 0.f, 0.f, 0.f};
    const int qrow = q0 + wave * 16 + quad * 4;
    for (int kt = 0; kt < NKT; ++kt) {
        const int kv0 = kt * BN;
        __syncthreads();
        #pragma unroll
        for (int it = 0; it < 4; ++it) {
            int row = 16 * it + rp;
            *(bf16x8*)(&KsP[row * KS_STRIDE + kcol]) =
                cvt8(K + base + (size_t)(kv0 + row) * DH + kcol);
        }
        {
            float4 vreg[8];
            #pragma unroll
            for (int rr = 0; rr < 8; ++rr)
                vreg[rr] = *(const float4*)(V + base + (size_t)(kv0 + kvb * 8 + rr) * DH + db * 4);
            #pragma unroll
            for (int c = 0; c < 4; ++c) {
                bf16x8 w;
                #pragma unroll
                for (int j = 0; j < 8; ++j) w[j] = (__bf16)f4get(vreg[j], c);
                int d = db * 4 + c, s = (d ^ (d >> 3)) & 7;
                *(bf16x8*)(&Vts[d * VT_STRIDE + ((kvb ^ s) << 3)]) = w;
            }
        }
        __syncthreads();
        int am[4][4];
        #pragma unroll
        for (int i = 0; i < 4; ++i)
            #pragma unroll
            for (int t = 0; t < 4; ++t)
                am[i][t] = adj[(size_t)(qrow + i) * NSEQ + kv0 + t * 16 + n16];
        float sc[4][4];
        #pragma unroll
        for (int t = 0; t < 4; ++t) {
            f32x4 acc = (f32x4){0.f, 0.f, 0.f, 0.f};
            #pragma unroll
            for (int ks = 0; ks < 4; ++ks) {
                bf16x8 bfr = *(const bf16x8*)(&KsP[(t * 16 + n16) * KS_STRIDE + ks * 32 + quad * 8]);
                acc = __builtin_amdgcn_mfma_f32_16x16x32_bf16(qf[ks], bfr, acc, 0, 0, 0);
            }
            #pragma unroll
            for (int i = 0; i < 4; ++i) sc[t][i] = acc[i];
        }
        __syncthreads();
        #pragma unroll
        for (int i = 0; i < 4; ++i) {
            const int prow = wave * 16 + quad * 4 + i;
            float rowsum = 0.f;
            #pragma unroll
            for (int t = 0; t < 4; ++t) {
                float p = exp2f(sc[t][i] * C1 - C2);
                p = (am[i][t] > 0) ? p : 0.f;
                rowsum += p;
                KsP[prow * PS_STRIDE + t * 16 + n16] = (__bf16)p;
            }
            lp[i] += rowsum;
        }
        #pragma unroll
        for (int ks = 0; ks < 2; ++ks) {
            bf16x8 pf = *(const bf16x8*)(&KsP[(wave * 16 + n16) * PS_STRIDE + ks * 32 + quad * 8]);
            #pragma unroll
            for (int nt = 0; nt < 8; ++nt) {
                int d = nt * 16 + n16, s = (d ^ (d >> 3)) & 7, kvbr = ks * 4 + quad;
                bf16x8 vf = *(const bf16x8*)(&Vts[d * VT_STRIDE + ((kvbr ^ s) << 3)]);
                o[nt] = __builtin_amdgcn_mfma_f32_16x16x32_bf16(pf, vf, o[nt], 0, 0, 0);
            }
        }
    }
    float linv[4];
    #pragma unroll
    for (int i = 0; i < 4; ++i) {
        float ls = lp[i];
        ls += __shfl_xor(ls, 1); ls += __shfl_xor(ls, 2);
        ls += __shfl_xor(ls, 4); ls += __shfl_xor(ls, 8);
        linv[i] = 1.0f / fmaxf(ls, 1e-30f);
    }
    #pragma unroll
    for (int nt = 0; nt < 8; ++nt)
        #pragma unroll
        for (int i = 0; i < 4; ++i)
            out[base + (size_t)(qrow + i) * DH + nt * 16 + n16] = o[nt][i] * linv[i];
}

extern "C" void kernel_launch(void* const* d_in, const int* in_sizes, int n_in,
                              void* d_out, int out_size, void* d_ws, size_t ws_size,
                              hipStream_t stream) {
    const float* Q   = (const float*)d_in[0];
    const float* K   = (const float*)d_in[1];
    const float* V   = (const float*)d_in[2];
    const int*   adj = (const int*)d_in[3];
    float* out = (float*)d_out;
    const size_t nKV  = (size_t)2 * 64 * NT2 * TILE2 * sizeof(__bf16);  // 33.55 MB
    const size_t nAdj = (size_t)NSEQ * 32 * sizeof(u32);                // 128 KB
    if (ws_size >= nKV + nAdj) {
        __bf16* Kws = (__bf16*)d_ws;
        __bf16* Vws = Kws + (size_t)64 * NT2 * TILE2;
        u32* adjc = (u32*)(Vws + (size_t)64 * NT2 * TILE2);
        prepack2<<<640, 256, 0, stream>>>(K, V, Kws, Vws, adjc, adj);
        attn_big<<<512, 1024, 0, stream>>>(Q, Kws, Vws, adjc, out);
    } else {
        attn_fallback<<<1024, 256, 0, stream>>>(Q, K, V, adj, out);
    }
}